// Round 1
// baseline (577.182 us; speedup 1.0000x reference)
//
#include <hip/hip_runtime.h>
#include <math.h>

// Decoder: embed -> GRU x2 -> adaptive log-softmax. B=256, E=512, H=1024,
// V=128000, tail1 N=127988 K=64.
// R3 structure: 10 launches, all GEMMs are LDS-free direct-fragment-load bf16.
//  1. prep        (one-shot f32->bf16: weights, gathered emb rows, hidden)
//  2. gru_gemm L0 (direct-frag, split z = side*2+khalf)
//  3. gru_gate L0 (also emits bf16 h0 for next gemm)
//  4. gru_gemm L1
//  5. gru_gate L1
//  6. small_gemm  (head_w+t0_proj+t1_proj padded to N=384, split-K 2)
//  7. postproc    (head log-softmax, c0 cluster, abuf -> bf16)
//  8. big_pass1   (tail exp-sums; fused single W f32->bf16, written for pass2)
//  9. reduce
// 10. big_pass2   (reads bf16 W from L3, writes final = v + rowOff)

typedef __attribute__((ext_vector_type(8))) short frag_ab;   // 8 bf16
typedef __attribute__((ext_vector_type(4))) float frag_cd;   // 4 fp32
typedef __attribute__((ext_vector_type(4))) float floatx4;
typedef __attribute__((ext_vector_type(4))) unsigned short ushortx4;

__device__ __forceinline__ unsigned short f2bf(float f) {
    unsigned int u = __builtin_bit_cast(unsigned int, f);
    u += 0x7fffu + ((u >> 16) & 1u);   // RNE
    return (unsigned short)(u >> 16);
}

// bf16 workspace region offsets (in ushorts, relative to usbase)
#define XB_OFF      0u          // [256][512]   gathered emb rows
#define HB0_OFF     131072u     // [256][1024]  hidden[0]
#define HB1_OFF     393216u     // [256][1024]  hidden[1]
#define H0B_OFF     655360u     // [256][1024]  h0 (gate L0 output)
#define H1B_OFF     917504u     // [256][1024]  h1 (gate L1 output)
#define ABUF_OFF    1179648u    // [256][64]    t1 projection
#define WIH0_OFF    1196032u    // [3072][512]
#define WHH0_OFF    2768896u    // [3072][1024]
#define WIH1_OFF    5914624u    // [3072][1024]
#define WHH1_OFF    9060352u    // [3072][1024]
#define WSM_OFF     12206080u   // [384][1024]  head_w/t0_proj/t1_proj, zero-pad
#define WT1_OFF     12599296u   // [128000][64] tail weights (pass1 writes)

// ---------------------------------------------------------------------------
// prep: one-shot f32 -> bf16 of everything the GEMMs read. 3,014,656 float4s.
// ---------------------------------------------------------------------------
__global__ __launch_bounds__(256) void prep(const int* __restrict__ idx,
                                            const float* __restrict__ emb,
                                            const float* __restrict__ hidden,
                                            const float* __restrict__ w_ih0,
                                            const float* __restrict__ w_hh0,
                                            const float* __restrict__ w_ih1,
                                            const float* __restrict__ w_hh1,
                                            const float* __restrict__ head_w,
                                            const float* __restrict__ t0_proj,
                                            const float* __restrict__ t1_proj,
                                            unsigned short* __restrict__ dst) {
    for (int i = blockIdx.x * 256 + threadIdx.x; i < 3014656; i += gridDim.x * 256) {
        const float* src;
        unsigned short* d;
        if (i < 1179648) {
            if (i < 393216) { src = w_ih0 + (size_t)i * 4; d = dst + WIH0_OFF + (size_t)i * 4; }
            else { int j = i - 393216; src = w_hh0 + (size_t)j * 4; d = dst + WHH0_OFF + (size_t)j * 4; }
        } else if (i < 2752512) {
            if (i < 1966080) { int j = i - 1179648; src = w_ih1 + (size_t)j * 4; d = dst + WIH1_OFF + (size_t)j * 4; }
            else { int j = i - 1966080; src = w_hh1 + (size_t)j * 4; d = dst + WHH1_OFF + (size_t)j * 4; }
        } else if (i < 2850816) {
            int j = i - 2752512;            // [384 rows][256 vec4/row]
            int row = j >> 8, cv = (j & 255) * 4;
            d = dst + WSM_OFF + (size_t)j * 4;
            if (row < 12)       src = head_w + (size_t)row * 1024 + cv;
            else if (row < 268) src = t0_proj + (size_t)(row - 12) * 1024 + cv;
            else if (row < 332) src = t1_proj + (size_t)(row - 268) * 1024 + cv;
            else                src = nullptr;      // zero pad rows 332..383
        } else if (i < 2883584) {
            int j = i - 2850816;            // [256 rows][128 vec4/row] emb gather
            int b = j >> 7, cv = (j & 127) * 4;
            src = emb + (size_t)idx[b] * 512 + cv;
            d = dst + XB_OFF + (size_t)j * 4;
        } else if (i < 2949120) {
            int j = i - 2883584; src = hidden + (size_t)j * 4; d = dst + HB0_OFF + (size_t)j * 4;
        } else {
            int j = i - 2949120; src = hidden + 262144 + (size_t)j * 4; d = dst + HB1_OFF + (size_t)j * 4;
        }
        floatx4 v = {0.f, 0.f, 0.f, 0.f};
        if (src) v = *(const floatx4*)src;
        ushortx4 o;
        o[0] = f2bf(v[0]); o[1] = f2bf(v[1]); o[2] = f2bf(v[2]); o[3] = f2bf(v[3]);
        *(ushortx4*)d = o;
    }
}

// ---------------------------------------------------------------------------
// GRU gemm: C[z] = A_side[256,K] @ W_side[3072,K]^T, z = side*2 + khalf.
// bf16 inputs, LDS-free: fragments loaded directly from global (8 contiguous
// k-elems per lane at row l16, k-offset quad*8 — matches mfma_16x16x32 layout).
// ---------------------------------------------------------------------------
__global__ __launch_bounds__(256) void gru_gemm(const unsigned short* __restrict__ A_ih,
                                                const unsigned short* __restrict__ A_hh,
                                                const unsigned short* __restrict__ W_ih,
                                                const unsigned short* __restrict__ W_hh,
                                                float* __restrict__ outbase,
                                                int Kih, int Khh) {
    const int z = blockIdx.z;
    const int side = z >> 1, half = z & 1;
    const int K = side ? Khh : Kih;
    const int Kh = K >> 1;
    const unsigned short* A = side ? A_hh : A_ih;
    const unsigned short* W = side ? W_hh : W_ih;
    float* C = outbase + (size_t)z * 786432;

    const int m0 = blockIdx.y * 64, n0 = blockIdx.x * 64;
    const int t = threadIdx.x;
    const int lane = t & 63, wid = t >> 6;
    const int wm = wid >> 1, wn = wid & 1;
    const int quad = lane >> 4, l16 = lane & 15;

    const unsigned short* ap0 = A + (size_t)(m0 + wm * 32 + l16) * K + half * Kh + quad * 8;
    const unsigned short* ap1 = ap0 + (size_t)16 * K;
    const unsigned short* bp0 = W + (size_t)(n0 + wn * 32 + l16) * K + half * Kh + quad * 8;
    const unsigned short* bp1 = bp0 + (size_t)16 * K;

    frag_cd zero4 = {0.f, 0.f, 0.f, 0.f};
    frag_cd acc[2][2] = {{zero4, zero4}, {zero4, zero4}};
#pragma unroll 4
    for (int k0 = 0; k0 < Kh; k0 += 32) {
        frag_ab a0 = *(const frag_ab*)(ap0 + k0);
        frag_ab a1 = *(const frag_ab*)(ap1 + k0);
        frag_ab b0 = *(const frag_ab*)(bp0 + k0);
        frag_ab b1 = *(const frag_ab*)(bp1 + k0);
        acc[0][0] = __builtin_amdgcn_mfma_f32_16x16x32_bf16(a0, b0, acc[0][0], 0, 0, 0);
        acc[0][1] = __builtin_amdgcn_mfma_f32_16x16x32_bf16(a0, b1, acc[0][1], 0, 0, 0);
        acc[1][0] = __builtin_amdgcn_mfma_f32_16x16x32_bf16(a1, b0, acc[1][0], 0, 0, 0);
        acc[1][1] = __builtin_amdgcn_mfma_f32_16x16x32_bf16(a1, b1, acc[1][1], 0, 0, 0);
    }
#pragma unroll
    for (int tm = 0; tm < 2; tm++)
#pragma unroll
        for (int tn = 0; tn < 2; tn++) {
            int col = n0 + wn * 32 + tn * 16 + l16;
#pragma unroll
            for (int r = 0; r < 4; r++) {
                int row = m0 + wm * 32 + tm * 16 + quad * 4 + r;
                C[(size_t)row * 3072 + col] = acc[tm][tn][r];
            }
        }
}

// ---------------------------------------------------------------------------
// GRU gate combine; sums split-K partials, adds biases, writes f32 + bf16 h.
// ---------------------------------------------------------------------------
__global__ __launch_bounds__(256) void gru_gate(const float* __restrict__ P,
                                                const float* __restrict__ b_ih,
                                                const float* __restrict__ b_hh,
                                                const float* __restrict__ hprev,
                                                float* __restrict__ hout,
                                                unsigned short* __restrict__ hb) {
    int idx = blockIdx.x * 256 + threadIdx.x;   // 256*1024
    int b = idx >> 10, j = idx & 1023;
    const float* g = P + (size_t)b * 3072 + j;
    float ir  = g[0]    + g[786432]        + b_ih[j];
    float iz  = g[1024] + g[786432 + 1024] + b_ih[1024 + j];
    float in_ = g[2048] + g[786432 + 2048] + b_ih[2048 + j];
    const float* gh = g + 2 * 786432;
    float hr  = gh[0]    + gh[786432]        + b_hh[j];
    float hz  = gh[1024] + gh[786432 + 1024] + b_hh[1024 + j];
    float hn  = gh[2048] + gh[786432 + 2048] + b_hh[2048 + j];
    float r = 1.f / (1.f + __expf(-(ir + hr)));
    float z = 1.f / (1.f + __expf(-(iz + hz)));
    float n = tanhf(in_ + r * hn);
    float v = (1.f - z) * n + z * hprev[idx];
    hout[idx] = v;
    hb[idx] = f2bf(v);
}

// ---------------------------------------------------------------------------
// Small combined gemm: C[256, 384] = h1 @ Wsm^T (bf16, padded), split-K 2.
// ---------------------------------------------------------------------------
__global__ __launch_bounds__(256) void small_gemm(const unsigned short* __restrict__ A,
                                                  const unsigned short* __restrict__ Wsm,
                                                  float* __restrict__ c_p) {
    const int K = 1024, Kh = 512;
    const int half = blockIdx.z;
    float* C = c_p + (size_t)half * 98304;

    const int m0 = blockIdx.y * 64, n0 = blockIdx.x * 64;
    const int t = threadIdx.x;
    const int lane = t & 63, wid = t >> 6;
    const int wm = wid >> 1, wn = wid & 1;
    const int quad = lane >> 4, l16 = lane & 15;

    const unsigned short* ap0 = A + (size_t)(m0 + wm * 32 + l16) * K + half * Kh + quad * 8;
    const unsigned short* ap1 = ap0 + (size_t)16 * K;
    const unsigned short* bp0 = Wsm + (size_t)(n0 + wn * 32 + l16) * K + half * Kh + quad * 8;
    const unsigned short* bp1 = bp0 + (size_t)16 * K;

    frag_cd zero4 = {0.f, 0.f, 0.f, 0.f};
    frag_cd acc[2][2] = {{zero4, zero4}, {zero4, zero4}};
#pragma unroll 4
    for (int k0 = 0; k0 < Kh; k0 += 32) {
        frag_ab a0 = *(const frag_ab*)(ap0 + k0);
        frag_ab a1 = *(const frag_ab*)(ap1 + k0);
        frag_ab b0 = *(const frag_ab*)(bp0 + k0);
        frag_ab b1 = *(const frag_ab*)(bp1 + k0);
        acc[0][0] = __builtin_amdgcn_mfma_f32_16x16x32_bf16(a0, b0, acc[0][0], 0, 0, 0);
        acc[0][1] = __builtin_amdgcn_mfma_f32_16x16x32_bf16(a0, b1, acc[0][1], 0, 0, 0);
        acc[1][0] = __builtin_amdgcn_mfma_f32_16x16x32_bf16(a1, b0, acc[1][0], 0, 0, 0);
        acc[1][1] = __builtin_amdgcn_mfma_f32_16x16x32_bf16(a1, b1, acc[1][1], 0, 0, 0);
    }
#pragma unroll
    for (int tm = 0; tm < 2; tm++)
#pragma unroll
        for (int tn = 0; tn < 2; tn++) {
            int col = n0 + wn * 32 + tn * 16 + l16;   // < 384 always
#pragma unroll
            for (int r = 0; r < 4; r++) {
                int row = m0 + wm * 32 + tm * 16 + quad * 4 + r;
                C[(size_t)row * 384 + col] = acc[tm][tn][r];
            }
        }
}

// ---------------------------------------------------------------------------
// postproc: per b — sum split-K halves; head log-softmax (cols 0..9);
// c0 cluster (cols 10,11); abuf (bf16) = t1 projection; stash head_lp[11].
// ---------------------------------------------------------------------------
__global__ __launch_bounds__(256) void postproc(const float* __restrict__ c_p,
                                                const float* __restrict__ t0_out,
                                                float* __restrict__ outp,
                                                unsigned short* __restrict__ abuf,
                                                float* __restrict__ h11buf) {
    int b = blockIdx.x, t = threadIdx.x;
    __shared__ float c[332];
    __shared__ float a0s[4], a1s[4];
    __shared__ float sh_lse;
    for (int j = t; j < 332; j += 256)
        c[j] = c_p[(size_t)b * 384 + j] + c_p[98304 + (size_t)b * 384 + j];
    __syncthreads();
    if (t == 0) {
        float m = c[0];
        for (int i = 1; i < 12; i++) m = fmaxf(m, c[i]);
        float se = 0.f;
        for (int i = 0; i < 12; i++) se += __expf(c[i] - m);
        sh_lse = m + logf(se);
    }
    __syncthreads();
    if (t < 10) outp[(size_t)b * 128000 + t] = c[t] - sh_lse;
    if (t < 64) abuf[(size_t)b * 64 + t] = f2bf(c[268 + t]);

    float pv = c[12 + t];
    float s0 = pv * t0_out[t];
    float s1 = pv * t0_out[256 + t];
    s0 += __shfl_xor(s0, 1);  s0 += __shfl_xor(s0, 2);  s0 += __shfl_xor(s0, 4);
    s0 += __shfl_xor(s0, 8);  s0 += __shfl_xor(s0, 16); s0 += __shfl_xor(s0, 32);
    s1 += __shfl_xor(s1, 1);  s1 += __shfl_xor(s1, 2);  s1 += __shfl_xor(s1, 4);
    s1 += __shfl_xor(s1, 8);  s1 += __shfl_xor(s1, 16); s1 += __shfl_xor(s1, 32);
    if ((t & 63) == 0) { a0s[t >> 6] = s0; a1s[t >> 6] = s1; }
    __syncthreads();
    if (t == 0) {
        float l0 = a0s[0] + a0s[1] + a0s[2] + a0s[3];
        float l1 = a1s[0] + a1s[1] + a1s[2] + a1s[3];
        float m = fmaxf(l0, l1);
        float lse2 = m + logf(__expf(l0 - m) + __expf(l1 - m));
        float hp = c[10] - sh_lse;
        outp[(size_t)b * 128000 + 10] = l0 - lse2 + hp;
        outp[(size_t)b * 128000 + 11] = l1 - lse2 + hp;
        h11buf[b] = c[11] - sh_lse;
    }
}

// ---------------------------------------------------------------------------
// big tail pass 1: exp-sums. Block = M=256 x N=16 tiles (4 per block), wave w
// owns rows 64w..64w+63 with A frags in registers; W converted f32->bf16 once
// here (wave 0 stores the bf16 copy for pass 2). No LDS, no syncthreads.
// ---------------------------------------------------------------------------
__global__ __launch_bounds__(256) void big_pass1(const unsigned short* __restrict__ Ab,
                                                 const float* __restrict__ W,
                                                 unsigned short* __restrict__ Wb,
                                                 float* __restrict__ partials) {
    const int N = 127988;
    const int t = threadIdx.x;
    const int lane = t & 63, wid = t >> 6;
    const int quad = lane >> 4, l16 = lane & 15;

    frag_ab a[4][2];
#pragma unroll
    for (int mf = 0; mf < 4; mf++)
#pragma unroll
        for (int kf = 0; kf < 2; kf++)
            a[mf][kf] = *(const frag_ab*)(Ab + (size_t)(wid * 64 + mf * 16 + l16) * 64 + kf * 32 + quad * 8);

    float rs[4][4] = {};
    for (int tt = 0; tt < 4; tt++) {
        const int n0 = (blockIdx.x * 4 + tt) * 16;
        const int nr = n0 + l16;
        frag_ab bw0 = {0, 0, 0, 0, 0, 0, 0, 0};
        frag_ab bw1 = {0, 0, 0, 0, 0, 0, 0, 0};
        if (nr < N) {
            const float* wp = W + (size_t)nr * 64 + quad * 8;
            floatx4 w0 = *(const floatx4*)wp;
            floatx4 w1 = *(const floatx4*)(wp + 4);
            floatx4 w2 = *(const floatx4*)(wp + 32);
            floatx4 w3 = *(const floatx4*)(wp + 36);
#pragma unroll
            for (int i = 0; i < 4; i++) {
                bw0[i]     = (short)f2bf(w0[i]);
                bw0[4 + i] = (short)f2bf(w1[i]);
                bw1[i]     = (short)f2bf(w2[i]);
                bw1[4 + i] = (short)f2bf(w3[i]);
            }
        }
        if (wid == 0) {   // nr < 128000 always; rows >= N stored as zeros
            unsigned short* wd = Wb + (size_t)nr * 64 + quad * 8;
            *(frag_ab*)wd = bw0;
            *(frag_ab*)(wd + 32) = bw1;
        }
        frag_cd zero4 = {0.f, 0.f, 0.f, 0.f};
        frag_cd acc[4] = {zero4, zero4, zero4, zero4};
#pragma unroll
        for (int mf = 0; mf < 4; mf++) {
            acc[mf] = __builtin_amdgcn_mfma_f32_16x16x32_bf16(a[mf][0], bw0, acc[mf], 0, 0, 0);
            acc[mf] = __builtin_amdgcn_mfma_f32_16x16x32_bf16(a[mf][1], bw1, acc[mf], 0, 0, 0);
        }
        if (nr < N) {
#pragma unroll
            for (int mf = 0; mf < 4; mf++)
#pragma unroll
                for (int r = 0; r < 4; r++)
                    rs[mf][r] += __expf(acc[mf][r]);
        }
    }
#pragma unroll
    for (int mf = 0; mf < 4; mf++)
#pragma unroll
        for (int r = 0; r < 4; r++) {
            float s = rs[mf][r];
            s += __shfl_xor(s, 1); s += __shfl_xor(s, 2);
            s += __shfl_xor(s, 4); s += __shfl_xor(s, 8);
            if (l16 == 0)
                partials[(size_t)(wid * 64 + mf * 16 + quad * 4 + r) * 2048 + blockIdx.x] = s;
        }
}

// ---------------------------------------------------------------------------
// reduce partials -> rowOff[b] = head_lp[11] - log(sum)
// ---------------------------------------------------------------------------
__global__ __launch_bounds__(256) void reduce_kernel(const float* __restrict__ partials,
                                                     const float* __restrict__ h11buf,
                                                     float* __restrict__ rowOff) {
    int b = blockIdx.x, t = threadIdx.x;
    __shared__ float a[4];
    float s = 0.f;
    for (int k = t; k < 2000; k += 256) s += partials[(size_t)b * 2048 + k];
    s += __shfl_xor(s, 1);  s += __shfl_xor(s, 2);  s += __shfl_xor(s, 4);
    s += __shfl_xor(s, 8);  s += __shfl_xor(s, 16); s += __shfl_xor(s, 32);
    if ((t & 63) == 0) a[t >> 6] = s;
    __syncthreads();
    if (t == 0) rowOff[b] = h11buf[b] - logf(a[0] + a[1] + a[2] + a[3]);
}

// ---------------------------------------------------------------------------
// big tail pass 2: same structure, bf16 W from pass1, writes final logprobs.
// ---------------------------------------------------------------------------
__global__ __launch_bounds__(256) void big_pass2(const unsigned short* __restrict__ Ab,
                                                 const unsigned short* __restrict__ Wb,
                                                 const float* __restrict__ rowOff,
                                                 float* __restrict__ outp) {
    const int N = 127988;
    const int t = threadIdx.x;
    const int lane = t & 63, wid = t >> 6;
    const int quad = lane >> 4, l16 = lane & 15;

    frag_ab a[4][2];
#pragma unroll
    for (int mf = 0; mf < 4; mf++)
#pragma unroll
        for (int kf = 0; kf < 2; kf++)
            a[mf][kf] = *(const frag_ab*)(Ab + (size_t)(wid * 64 + mf * 16 + l16) * 64 + kf * 32 + quad * 8);

    float ro[4][4];
#pragma unroll
    for (int mf = 0; mf < 4; mf++)
#pragma unroll
        for (int r = 0; r < 4; r++)
            ro[mf][r] = rowOff[wid * 64 + mf * 16 + quad * 4 + r];

    for (int tt = 0; tt < 4; tt++) {
        const int n0 = (blockIdx.x * 4 + tt) * 16;
        const int nr = n0 + l16;
        const unsigned short* wp = Wb + (size_t)nr * 64 + quad * 8;
        frag_ab bw0 = *(const frag_ab*)wp;
        frag_ab bw1 = *(const frag_ab*)(wp + 32);
        frag_cd zero4 = {0.f, 0.f, 0.f, 0.f};
        frag_cd acc[4] = {zero4, zero4, zero4, zero4};
#pragma unroll
        for (int mf = 0; mf < 4; mf++) {
            acc[mf] = __builtin_amdgcn_mfma_f32_16x16x32_bf16(a[mf][0], bw0, acc[mf], 0, 0, 0);
            acc[mf] = __builtin_amdgcn_mfma_f32_16x16x32_bf16(a[mf][1], bw1, acc[mf], 0, 0, 0);
        }
        if (nr < N) {
#pragma unroll
            for (int mf = 0; mf < 4; mf++)
#pragma unroll
                for (int r = 0; r < 4; r++)
                    outp[(size_t)(wid * 64 + mf * 16 + quad * 4 + r) * 128000 + 12 + nr] =
                        acc[mf][r] + ro[mf][r];
        }
    }
}

extern "C" void kernel_launch(void* const* d_in, const int* in_sizes, int n_in,
                              void* d_out, int out_size, void* d_ws, size_t ws_size,
                              hipStream_t stream) {
    const int*   input  = (const int*)d_in[0];
    const float* hidden = (const float*)d_in[1];
    const float* emb    = (const float*)d_in[3];
    const float* w_ih0  = (const float*)d_in[4];
    const float* w_hh0  = (const float*)d_in[5];
    const float* b_ih0  = (const float*)d_in[6];
    const float* b_hh0  = (const float*)d_in[7];
    const float* w_ih1  = (const float*)d_in[8];
    const float* w_hh1  = (const float*)d_in[9];
    const float* b_ih1  = (const float*)d_in[10];
    const float* b_hh1  = (const float*)d_in[11];
    const float* head_w = (const float*)d_in[12];
    const float* t0_proj = (const float*)d_in[13];
    const float* t0_out  = (const float*)d_in[14];
    const float* t1_proj = (const float*)d_in[15];
    const float* t1_out  = (const float*)d_in[16];

    float* outp = (float*)d_out;
    float* ws   = (float*)d_ws;

    float* gruws    = ws;                       // 4 * 786432 f32 (split partials)
    float* c_p      = gruws + 3145728;          // 2 * 98304
    float* partials = c_p + 196608;             // 256 * 2048
    float* h11buf   = partials + 524288;        // 256
    float* rowOff   = h11buf + 256;             // 256
    unsigned short* us = (unsigned short*)(rowOff + 256);   // bf16 arena

    unsigned short* xb    = us + XB_OFF;
    unsigned short* hb0   = us + HB0_OFF;
    unsigned short* hb1   = us + HB1_OFF;
    unsigned short* h0b   = us + H0B_OFF;
    unsigned short* h1b   = us + H1B_OFF;
    unsigned short* abufb = us + ABUF_OFF;
    unsigned short* wih0  = us + WIH0_OFF;
    unsigned short* whh0  = us + WHH0_OFF;
    unsigned short* wih1  = us + WIH1_OFF;
    unsigned short* whh1  = us + WHH1_OFF;
    unsigned short* wsm   = us + WSM_OFF;
    unsigned short* wt1   = us + WT1_OFF;

    float* h0 = outp + 32768000;                // new_hidden[0]
    float* h1 = h0 + 262144;                    // new_hidden[1]

    prep<<<2048, 256, 0, stream>>>(input, emb, hidden, w_ih0, w_hh0, w_ih1, w_hh1,
                                   head_w, t0_proj, t1_proj, us);
    gru_gemm<<<dim3(48, 4, 4), 256, 0, stream>>>(xb, hb0, wih0, whh0, gruws, 512, 1024);
    gru_gate<<<1024, 256, 0, stream>>>(gruws, b_ih0, b_hh0, hidden, h0, h0b);
    gru_gemm<<<dim3(48, 4, 4), 256, 0, stream>>>(h0b, hb1, wih1, whh1, gruws, 1024, 1024);
    gru_gate<<<1024, 256, 0, stream>>>(gruws, b_ih1, b_hh1, hidden + 262144, h1, h1b);
    small_gemm<<<dim3(6, 4, 2), 256, 0, stream>>>(h1b, wsm, c_p);
    postproc<<<256, 256, 0, stream>>>(c_p, t0_out, outp, abufb, h11buf);
    big_pass1<<<2000, 256, 0, stream>>>(abufb, t1_out, wt1, partials);
    reduce_kernel<<<256, 256, 0, stream>>>(partials, h11buf, rowOff);
    big_pass2<<<2000, 256, 0, stream>>>(abufb, wt1, rowOff, outp);
}

// Round 2
// 516.105 us; speedup vs baseline: 1.1183x; 1.1183x over previous
//
#include <hip/hip_runtime.h>
#include <math.h>

// Decoder: embed -> GRU x2 -> adaptive log-softmax. B=256, E=512, H=1024,
// V=128000, tail1 N=127988 K=64.
// R4 = R2 (proven 519 us) + two surgical changes:
//  - gru_gemm / small_gemm: double-buffered LDS, ONE barrier per K-step,
//    next-step global loads issued after the barrier (overlap MFMA+convert).
//  - big_pass2: epilogue stages C-tile in LDS (stride 68) and stores with
//    64-lane 256B runs instead of 16-lane 64B runs.
// Launch structure (9 launches) identical to R2.

#define BM 64
#define BN 64
#define BK 32

typedef __attribute__((ext_vector_type(8))) short frag_ab;   // 8 bf16
typedef __attribute__((ext_vector_type(4))) float frag_cd;   // 4 fp32
typedef __attribute__((ext_vector_type(4))) float floatx4;

__device__ __forceinline__ unsigned short f2bf(float f) {
    unsigned int u = __builtin_bit_cast(unsigned int, f);
    u += 0x7fffu + ((u >> 16) & 1u);   // RNE
    return (unsigned short)(u >> 16);
}

// ---------------------------------------------------------------------------
// GRU gemm: C[z] = A_side[256,K] @ W_side[3072,K]^T, z = side*2 + khalf.
// Double-buffered LDS, 1 barrier/step, loads for step s+1 issued after the
// barrier of step s so they complete under the MFMA phase.
// ---------------------------------------------------------------------------
__global__ __launch_bounds__(256) void gru_gemm(const int* __restrict__ idx,
                                                const float* __restrict__ A_ih,
                                                const float* __restrict__ A_hh,
                                                const float* __restrict__ W_ih,
                                                const float* __restrict__ W_hh,
                                                float* __restrict__ outbase,
                                                int Kih, int Khh) {
    const int z = blockIdx.z;
    const int side = z >> 1, half = z & 1;
    const int K = side ? Khh : Kih;
    const int Kh = K >> 1;
    const float* A = side ? A_hh : A_ih;
    const float* W = side ? W_hh : W_ih;
    float* C = outbase + (size_t)z * 786432;

    __shared__ unsigned short As[2][BM * BK];
    __shared__ unsigned short Wsh[2][BN * BK];
    const int m0 = blockIdx.y * BM, n0 = blockIdx.x * BN;
    const int t = threadIdx.x;
    const int lane = t & 63, wid = t >> 6;
    const int wm = wid >> 1, wn = wid & 1;
    const int quad = lane >> 4, l16 = lane & 15;
    const int lr = t >> 2;          // 0..63 tile row
    const int lc = (t & 3) * 8;     // 0/8/16/24 k-offset

    const int m = m0 + lr;
    const float* arow = (side == 0 && idx) ? A + (size_t)idx[m] * K
                                           : A + (size_t)m * K;
    arow += (size_t)half * Kh + lc;
    const float* wrow = W + (size_t)(n0 + lr) * K + (size_t)half * Kh + lc;

    frag_cd zero4 = {0.f, 0.f, 0.f, 0.f};
    frag_cd acc[2][2] = {{zero4, zero4}, {zero4, zero4}};

    const int nsteps = Kh >> 5;     // BK=32

    // prologue: load + convert + stage step 0 into buffer 0
    floatx4 a0 = *(const floatx4*)(arow);
    floatx4 a1 = *(const floatx4*)(arow + 4);
    floatx4 w0 = *(const floatx4*)(wrow);
    floatx4 w1 = *(const floatx4*)(wrow + 4);
    {
        frag_ab apk, wpk;
#pragma unroll
        for (int i = 0; i < 4; i++) {
            apk[i]     = (short)f2bf(a0[i]);
            apk[4 + i] = (short)f2bf(a1[i]);
            wpk[i]     = (short)f2bf(w0[i]);
            wpk[4 + i] = (short)f2bf(w1[i]);
        }
        *(frag_ab*)&As[0][lr * BK + lc] = apk;
        *(frag_ab*)&Wsh[0][lr * BK + lc] = wpk;
    }

    int p = 0;
    for (int s = 0; s < nsteps; s++) {
        __syncthreads();                      // buf[p] ready for all waves
        if (s + 1 < nsteps) {                 // issue next loads AFTER barrier
            int k0 = (s + 1) * BK;
            a0 = *(const floatx4*)(arow + k0);
            a1 = *(const floatx4*)(arow + k0 + 4);
            w0 = *(const floatx4*)(wrow + k0);
            w1 = *(const floatx4*)(wrow + k0 + 4);
        }
        frag_ab bfr0 = *(const frag_ab*)&Wsh[p][(wn * 32 + l16) * BK + quad * 8];
        frag_ab bfr1 = *(const frag_ab*)&Wsh[p][(wn * 32 + 16 + l16) * BK + quad * 8];
        frag_ab af0  = *(const frag_ab*)&As[p][(wm * 32 + l16) * BK + quad * 8];
        frag_ab af1  = *(const frag_ab*)&As[p][(wm * 32 + 16 + l16) * BK + quad * 8];
        acc[0][0] = __builtin_amdgcn_mfma_f32_16x16x32_bf16(af0, bfr0, acc[0][0], 0, 0, 0);
        acc[0][1] = __builtin_amdgcn_mfma_f32_16x16x32_bf16(af0, bfr1, acc[0][1], 0, 0, 0);
        acc[1][0] = __builtin_amdgcn_mfma_f32_16x16x32_bf16(af1, bfr0, acc[1][0], 0, 0, 0);
        acc[1][1] = __builtin_amdgcn_mfma_f32_16x16x32_bf16(af1, bfr1, acc[1][1], 0, 0, 0);
        if (s + 1 < nsteps) {                 // convert + stage into buf[p^1]
            frag_ab apk, wpk;
#pragma unroll
            for (int i = 0; i < 4; i++) {
                apk[i]     = (short)f2bf(a0[i]);
                apk[4 + i] = (short)f2bf(a1[i]);
                wpk[i]     = (short)f2bf(w0[i]);
                wpk[4 + i] = (short)f2bf(w1[i]);
            }
            *(frag_ab*)&As[p ^ 1][lr * BK + lc] = apk;
            *(frag_ab*)&Wsh[p ^ 1][lr * BK + lc] = wpk;
        }
        p ^= 1;
    }
#pragma unroll
    for (int tm = 0; tm < 2; tm++)
#pragma unroll
        for (int tn = 0; tn < 2; tn++) {
            int col = n0 + wn * 32 + tn * 16 + l16;
#pragma unroll
            for (int r = 0; r < 4; r++) {
                int row = m0 + wm * 32 + tm * 16 + quad * 4 + r;
                C[(size_t)row * 3072 + col] = acc[tm][tn][r];
            }
        }
}

// ---------------------------------------------------------------------------
// GRU gate combine; sums split-K partials and adds biases here.
// ---------------------------------------------------------------------------
__global__ __launch_bounds__(256) void gru_gate(const float* __restrict__ P,
                                                const float* __restrict__ b_ih,
                                                const float* __restrict__ b_hh,
                                                const float* __restrict__ hprev,
                                                float* __restrict__ hout) {
    int idx = blockIdx.x * 256 + threadIdx.x;   // 256*1024
    int b = idx >> 10, j = idx & 1023;
    const float* g = P + (size_t)b * 3072 + j;
    float ir  = g[0]    + g[786432]        + b_ih[j];
    float iz  = g[1024] + g[786432 + 1024] + b_ih[1024 + j];
    float in_ = g[2048] + g[786432 + 2048] + b_ih[2048 + j];
    const float* gh = g + 2 * 786432;
    float hr  = gh[0]    + gh[786432]        + b_hh[j];
    float hz  = gh[1024] + gh[786432 + 1024] + b_hh[1024 + j];
    float hn  = gh[2048] + gh[786432 + 2048] + b_hh[2048 + j];
    float r = 1.f / (1.f + __expf(-(ir + hr)));
    float z = 1.f / (1.f + __expf(-(iz + hz)));
    float n = tanhf(in_ + r * hn);
    hout[idx] = (1.f - z) * n + z * hprev[idx];
}

// ---------------------------------------------------------------------------
// Small combined gemm: C[256, 332(+pad 384)] = h1 @ [head_w; t0_proj; t1_proj]^T
// split-K 2 (z = half). Same dbuf pipeline as gru_gemm.
// ---------------------------------------------------------------------------
__global__ __launch_bounds__(256) void small_gemm(const float* __restrict__ A,
                                                  const float* __restrict__ head_w,
                                                  const float* __restrict__ t0_proj,
                                                  const float* __restrict__ t1_proj,
                                                  float* __restrict__ c_p) {
    const int K = 1024, Kh = 512;
    const int half = blockIdx.z;
    float* C = c_p + (size_t)half * 98304;

    __shared__ unsigned short As[2][BM * BK];
    __shared__ unsigned short Wsh[2][BN * BK];
    const int m0 = blockIdx.y * BM, n0 = blockIdx.x * BN;
    const int t = threadIdx.x;
    const int lane = t & 63, wid = t >> 6;
    const int wm = wid >> 1, wn = wid & 1;
    const int quad = lane >> 4, l16 = lane & 15;
    const int lr = t >> 2;
    const int lc = (t & 3) * 8;

    const float* arow = A + (size_t)(m0 + lr) * K + (size_t)half * Kh + lc;
    int wr = n0 + lr;
    const float* wrow;
    if (wr < 12)       wrow = head_w  + (size_t)wr * K;
    else if (wr < 268) wrow = t0_proj + (size_t)(wr - 12) * K;
    else if (wr < 332) wrow = t1_proj + (size_t)(wr - 268) * K;
    else               wrow = nullptr;
    if (wrow) wrow += (size_t)half * Kh + lc;

    frag_cd zero4 = {0.f, 0.f, 0.f, 0.f};
    frag_cd acc[2][2] = {{zero4, zero4}, {zero4, zero4}};

    const int nsteps = Kh >> 5;

    floatx4 a0 = *(const floatx4*)(arow);
    floatx4 a1 = *(const floatx4*)(arow + 4);
    floatx4 w0 = {0.f, 0.f, 0.f, 0.f}, w1 = {0.f, 0.f, 0.f, 0.f};
    if (wrow) {
        w0 = *(const floatx4*)(wrow);
        w1 = *(const floatx4*)(wrow + 4);
    }
    {
        frag_ab apk, wpk;
#pragma unroll
        for (int i = 0; i < 4; i++) {
            apk[i]     = (short)f2bf(a0[i]);
            apk[4 + i] = (short)f2bf(a1[i]);
            wpk[i]     = (short)f2bf(w0[i]);
            wpk[4 + i] = (short)f2bf(w1[i]);
        }
        *(frag_ab*)&As[0][lr * BK + lc] = apk;
        *(frag_ab*)&Wsh[0][lr * BK + lc] = wpk;
    }

    int p = 0;
    for (int s = 0; s < nsteps; s++) {
        __syncthreads();
        if (s + 1 < nsteps) {
            int k0 = (s + 1) * BK;
            a0 = *(const floatx4*)(arow + k0);
            a1 = *(const floatx4*)(arow + k0 + 4);
            if (wrow) {
                w0 = *(const floatx4*)(wrow + k0);
                w1 = *(const floatx4*)(wrow + k0 + 4);
            }
        }
        frag_ab bfr0 = *(const frag_ab*)&Wsh[p][(wn * 32 + l16) * BK + quad * 8];
        frag_ab bfr1 = *(const frag_ab*)&Wsh[p][(wn * 32 + 16 + l16) * BK + quad * 8];
        frag_ab af0  = *(const frag_ab*)&As[p][(wm * 32 + l16) * BK + quad * 8];
        frag_ab af1  = *(const frag_ab*)&As[p][(wm * 32 + 16 + l16) * BK + quad * 8];
        acc[0][0] = __builtin_amdgcn_mfma_f32_16x16x32_bf16(af0, bfr0, acc[0][0], 0, 0, 0);
        acc[0][1] = __builtin_amdgcn_mfma_f32_16x16x32_bf16(af0, bfr1, acc[0][1], 0, 0, 0);
        acc[1][0] = __builtin_amdgcn_mfma_f32_16x16x32_bf16(af1, bfr0, acc[1][0], 0, 0, 0);
        acc[1][1] = __builtin_amdgcn_mfma_f32_16x16x32_bf16(af1, bfr1, acc[1][1], 0, 0, 0);
        if (s + 1 < nsteps) {
            frag_ab apk, wpk;
#pragma unroll
            for (int i = 0; i < 4; i++) {
                apk[i]     = (short)f2bf(a0[i]);
                apk[4 + i] = (short)f2bf(a1[i]);
                wpk[i]     = (short)f2bf(w0[i]);
                wpk[4 + i] = (short)f2bf(w1[i]);
            }
            *(frag_ab*)&As[p ^ 1][lr * BK + lc] = apk;
            *(frag_ab*)&Wsh[p ^ 1][lr * BK + lc] = wpk;
        }
        p ^= 1;
    }
#pragma unroll
    for (int tm = 0; tm < 2; tm++)
#pragma unroll
        for (int tn = 0; tn < 2; tn++) {
            int col = n0 + wn * 32 + tn * 16 + l16;   // < 384 always
#pragma unroll
            for (int r = 0; r < 4; r++) {
                int row = m0 + wm * 32 + tm * 16 + quad * 4 + r;
                C[(size_t)row * 384 + col] = acc[tm][tn][r];
            }
        }
}

// ---------------------------------------------------------------------------
// postproc: per b — sum split-K halves; head log-softmax (cols 0..9);
// c0 cluster (cols 10,11); extract abuf = t1 projection; stash head_lp[11].
// ---------------------------------------------------------------------------
__global__ __launch_bounds__(256) void postproc(const float* __restrict__ c_p,
                                                const float* __restrict__ t0_out,
                                                float* __restrict__ outp,
                                                float* __restrict__ abuf,
                                                float* __restrict__ h11buf) {
    int b = blockIdx.x, t = threadIdx.x;
    __shared__ float c[332];
    __shared__ float a0s[4], a1s[4];
    __shared__ float sh_lse;
    for (int j = t; j < 332; j += 256)
        c[j] = c_p[(size_t)b * 384 + j] + c_p[98304 + (size_t)b * 384 + j];
    __syncthreads();
    if (t == 0) {
        float m = c[0];
        for (int i = 1; i < 12; i++) m = fmaxf(m, c[i]);
        float se = 0.f;
        for (int i = 0; i < 12; i++) se += __expf(c[i] - m);
        sh_lse = m + logf(se);
    }
    __syncthreads();
    if (t < 10) outp[(size_t)b * 128000 + t] = c[t] - sh_lse;
    if (t < 64) abuf[(size_t)b * 64 + t] = c[268 + t];

    float pv = c[12 + t];
    float s0 = pv * t0_out[t];
    float s1 = pv * t0_out[256 + t];
    s0 += __shfl_xor(s0, 1);  s0 += __shfl_xor(s0, 2);  s0 += __shfl_xor(s0, 4);
    s0 += __shfl_xor(s0, 8);  s0 += __shfl_xor(s0, 16); s0 += __shfl_xor(s0, 32);
    s1 += __shfl_xor(s1, 1);  s1 += __shfl_xor(s1, 2);  s1 += __shfl_xor(s1, 4);
    s1 += __shfl_xor(s1, 8);  s1 += __shfl_xor(s1, 16); s1 += __shfl_xor(s1, 32);
    if ((t & 63) == 0) { a0s[t >> 6] = s0; a1s[t >> 6] = s1; }
    __syncthreads();
    if (t == 0) {
        float l0 = a0s[0] + a0s[1] + a0s[2] + a0s[3];
        float l1 = a1s[0] + a1s[1] + a1s[2] + a1s[3];
        float m = fmaxf(l0, l1);
        float lse2 = m + logf(__expf(l0 - m) + __expf(l1 - m));
        float hp = c[10] - sh_lse;
        outp[(size_t)b * 128000 + 10] = l0 - lse2 + hp;
        outp[(size_t)b * 128000 + 11] = l1 - lse2 + hp;
        h11buf[b] = c[11] - sh_lse;
    }
}

// ---------------------------------------------------------------------------
// big tail matmul pass 1: exp-sums only (no logits materialized).
// ---------------------------------------------------------------------------
__global__ __launch_bounds__(256) void big_pass1(const float* __restrict__ A,
                                                 const float* __restrict__ W,
                                                 float* __restrict__ partials) {
    const int N = 127988, K = 64;
    __shared__ unsigned short As[BM * BK];
    __shared__ unsigned short Wsh[BN * BK];
    __shared__ float rowsum[BM];
    const int m0 = blockIdx.y * BM, n0 = blockIdx.x * BN;
    const int t = threadIdx.x;
    const int lane = t & 63, wid = t >> 6;
    const int wm = wid >> 1, wn = wid & 1;
    const int quad = lane >> 4, l16 = lane & 15;
    const int lr = t >> 2;
    const int lc = (t & 3) * 8;

    if (t < BM) rowsum[t] = 0.f;

    const float* arow = A + (size_t)(m0 + lr) * K + lc;
    int wr = n0 + lr;
    const float* wrow = (wr < N) ? W + (size_t)wr * K + lc : nullptr;

    frag_cd zero4 = {0.f, 0.f, 0.f, 0.f};
    frag_cd acc[2][2] = {{zero4, zero4}, {zero4, zero4}};

    for (int k0 = 0; k0 < K; k0 += BK) {
        floatx4 a0 = *(const floatx4*)(arow + k0);
        floatx4 a1 = *(const floatx4*)(arow + k0 + 4);
        floatx4 w0 = {0.f, 0.f, 0.f, 0.f}, w1 = {0.f, 0.f, 0.f, 0.f};
        if (wrow) {
            w0 = *(const floatx4*)(wrow + k0);
            w1 = *(const floatx4*)(wrow + k0 + 4);
        }
        frag_ab apk, wpk;
#pragma unroll
        for (int i = 0; i < 4; i++) {
            apk[i]     = (short)f2bf(a0[i]);
            apk[4 + i] = (short)f2bf(a1[i]);
            wpk[i]     = (short)f2bf(w0[i]);
            wpk[4 + i] = (short)f2bf(w1[i]);
        }
        __syncthreads();
        *(frag_ab*)&As[lr * BK + lc] = apk;
        *(frag_ab*)&Wsh[lr * BK + lc] = wpk;
        __syncthreads();

        frag_ab bfr[2];
#pragma unroll
        for (int tn = 0; tn < 2; tn++)
            bfr[tn] = *(const frag_ab*)&Wsh[(wn * 32 + tn * 16 + l16) * BK + quad * 8];
#pragma unroll
        for (int tm = 0; tm < 2; tm++) {
            frag_ab af = *(const frag_ab*)&As[(wm * 32 + tm * 16 + l16) * BK + quad * 8];
#pragma unroll
            for (int tn = 0; tn < 2; tn++)
                acc[tm][tn] = __builtin_amdgcn_mfma_f32_16x16x32_bf16(af, bfr[tn], acc[tm][tn], 0, 0, 0);
        }
    }

#pragma unroll
    for (int tm = 0; tm < 2; tm++) {
#pragma unroll
        for (int r = 0; r < 4; r++) {
            float s = 0.f;
#pragma unroll
            for (int tn = 0; tn < 2; tn++) {
                int col = n0 + wn * 32 + tn * 16 + l16;
                if (col < N) s += __expf(acc[tm][tn][r]);
            }
            s += __shfl_xor(s, 1);
            s += __shfl_xor(s, 2);
            s += __shfl_xor(s, 4);
            s += __shfl_xor(s, 8);
            if (l16 == 0) atomicAdd(&rowsum[wm * 32 + tm * 16 + quad * 4 + r], s);
        }
    }
    __syncthreads();
    if (t < BM) partials[(size_t)(m0 + t) * 2048 + blockIdx.x] = rowsum[t];
}

// ---------------------------------------------------------------------------
// reduce partials -> rowOff[b] = head_lp[11] - log(sum)
// ---------------------------------------------------------------------------
__global__ __launch_bounds__(256) void reduce_kernel(const float* __restrict__ partials,
                                                     const float* __restrict__ h11buf,
                                                     float* __restrict__ rowOff) {
    int b = blockIdx.x, t = threadIdx.x;
    __shared__ float a[4];
    float s = 0.f;
    for (int k = t; k < 2000; k += 256) s += partials[(size_t)b * 2048 + k];
    s += __shfl_xor(s, 1);  s += __shfl_xor(s, 2);  s += __shfl_xor(s, 4);
    s += __shfl_xor(s, 8);  s += __shfl_xor(s, 16); s += __shfl_xor(s, 32);
    if ((t & 63) == 0) a[t >> 6] = s;
    __syncthreads();
    if (t == 0) rowOff[b] = h11buf[b] - logf(a[0] + a[1] + a[2] + a[3]);
}

// ---------------------------------------------------------------------------
// big tail matmul pass 2: recompute, write final = v + rowOff.
// Epilogue stages the 64x64 C-tile in LDS and stores with 256B runs.
// ---------------------------------------------------------------------------
__global__ __launch_bounds__(256) void big_pass2(const float* __restrict__ A,
                                                 const float* __restrict__ W,
                                                 const float* __restrict__ rowOff,
                                                 float* __restrict__ outp) {
    const int N = 127988, K = 64;
    __shared__ unsigned short As[BM * BK];
    __shared__ unsigned short Wsh[BN * BK];
    __shared__ float ro[BM];
    __shared__ float Cs[BM * 68];
    const int m0 = blockIdx.y * BM, n0 = blockIdx.x * BN;
    const int t = threadIdx.x;
    const int lane = t & 63, wid = t >> 6;
    const int wm = wid >> 1, wn = wid & 1;
    const int quad = lane >> 4, l16 = lane & 15;
    const int lr = t >> 2;
    const int lc = (t & 3) * 8;

    if (t < BM) ro[t] = rowOff[m0 + t];

    const float* arow = A + (size_t)(m0 + lr) * K + lc;
    int wr = n0 + lr;
    const float* wrow = (wr < N) ? W + (size_t)wr * K + lc : nullptr;

    frag_cd zero4 = {0.f, 0.f, 0.f, 0.f};
    frag_cd acc[2][2] = {{zero4, zero4}, {zero4, zero4}};

    for (int k0 = 0; k0 < K; k0 += BK) {
        floatx4 a0 = *(const floatx4*)(arow + k0);
        floatx4 a1 = *(const floatx4*)(arow + k0 + 4);
        floatx4 w0 = {0.f, 0.f, 0.f, 0.f}, w1 = {0.f, 0.f, 0.f, 0.f};
        if (wrow) {
            w0 = *(const floatx4*)(wrow + k0);
            w1 = *(const floatx4*)(wrow + k0 + 4);
        }
        frag_ab apk, wpk;
#pragma unroll
        for (int i = 0; i < 4; i++) {
            apk[i]     = (short)f2bf(a0[i]);
            apk[4 + i] = (short)f2bf(a1[i]);
            wpk[i]     = (short)f2bf(w0[i]);
            wpk[4 + i] = (short)f2bf(w1[i]);
        }
        __syncthreads();
        *(frag_ab*)&As[lr * BK + lc] = apk;
        *(frag_ab*)&Wsh[lr * BK + lc] = wpk;
        __syncthreads();

        frag_ab bfr[2];
#pragma unroll
        for (int tn = 0; tn < 2; tn++)
            bfr[tn] = *(const frag_ab*)&Wsh[(wn * 32 + tn * 16 + l16) * BK + quad * 8];
#pragma unroll
        for (int tm = 0; tm < 2; tm++) {
            frag_ab af = *(const frag_ab*)&As[(wm * 32 + tm * 16 + l16) * BK + quad * 8];
#pragma unroll
            for (int tn = 0; tn < 2; tn++)
                acc[tm][tn] = __builtin_amdgcn_mfma_f32_16x16x32_bf16(af, bfr[tn], acc[tm][tn], 0, 0, 0);
        }
    }

    // stage C-tile in LDS (stride 68 : 2-way max bank aliasing = free)
#pragma unroll
    for (int tm = 0; tm < 2; tm++)
#pragma unroll
        for (int tn = 0; tn < 2; tn++) {
            int col = wn * 32 + tn * 16 + l16;
#pragma unroll
            for (int r = 0; r < 4; r++)
                Cs[(wm * 32 + tm * 16 + quad * 4 + r) * 68 + col] = acc[tm][tn][r];
        }
    __syncthreads();

    // coalesced write-out: 64 consecutive lanes cover one 64-col row = 256B run
    for (int i = t; i < BM * BN; i += 256) {
        int rl = i >> 6, col = i & 63;
        int gc = n0 + col;
        if (gc < N)
            outp[(size_t)(m0 + rl) * 128000 + 12 + gc] = Cs[rl * 68 + col] + ro[rl];
    }
}

extern "C" void kernel_launch(void* const* d_in, const int* in_sizes, int n_in,
                              void* d_out, int out_size, void* d_ws, size_t ws_size,
                              hipStream_t stream) {
    const int*   input  = (const int*)d_in[0];
    const float* hidden = (const float*)d_in[1];
    const float* emb    = (const float*)d_in[3];
    const float* w_ih0  = (const float*)d_in[4];
    const float* w_hh0  = (const float*)d_in[5];
    const float* b_ih0  = (const float*)d_in[6];
    const float* b_hh0  = (const float*)d_in[7];
    const float* w_ih1  = (const float*)d_in[8];
    const float* w_hh1  = (const float*)d_in[9];
    const float* b_ih1  = (const float*)d_in[10];
    const float* b_hh1  = (const float*)d_in[11];
    const float* head_w = (const float*)d_in[12];
    const float* t0_proj = (const float*)d_in[13];
    const float* t0_out  = (const float*)d_in[14];
    const float* t1_proj = (const float*)d_in[15];
    const float* t1_out  = (const float*)d_in[16];

    float* outp = (float*)d_out;
    float* ws   = (float*)d_ws;

    float* gruws    = ws;                       // 4 * 786432
    float* c_p      = gruws + 4 * 786432;       // 2 * 98304
    float* abuf     = c_p + 2 * 98304;          // 16384
    float* h11buf   = abuf + 16384;             // 256
    float* rowOff   = h11buf + 256;             // 256
    float* partials = rowOff + 256;             // 256 * 2048

    float* h0 = outp + 32768000;                // new_hidden[0]
    float* h1 = h0 + 262144;                    // new_hidden[1]

    gru_gemm<<<dim3(48, 4, 4), 256, 0, stream>>>(input, emb, hidden,
                                                 w_ih0, w_hh0, gruws, 512, 1024);
    gru_gate<<<1024, 256, 0, stream>>>(gruws, b_ih0, b_hh0, hidden, h0);
    gru_gemm<<<dim3(48, 4, 4), 256, 0, stream>>>(nullptr, h0, hidden + 262144,
                                                 w_ih1, w_hh1, gruws, 1024, 1024);
    gru_gate<<<1024, 256, 0, stream>>>(gruws, b_ih1, b_hh1, hidden + 262144, h1);
    small_gemm<<<dim3(6, 4, 2), 256, 0, stream>>>(h1, head_w, t0_proj, t1_proj, c_p);
    postproc<<<256, 256, 0, stream>>>(c_p, t0_out, outp, abuf, h11buf);
    big_pass1<<<dim3(2000, 4), 256, 0, stream>>>(abuf, t1_out, partials);
    reduce_kernel<<<256, 256, 0, stream>>>(partials, h11buf, rowOff);
    big_pass2<<<dim3(2000, 4), 256, 0, stream>>>(abuf, t1_out, rowOff, outp);
}